// Round 5
// baseline (87.156 us; speedup 1.0000x reference)
//
#include <hip/hip_runtime.h>
#include <math.h>

#define BSZ 4
#define NN  256
#define CC  96

#define XIN_OFF  0
#define EH_OFF   2048          // BSZ*NN*2
#define COV_OFF  100352        // 2048 + BSZ*NN*CC

#define INV_SQRT_2PI 0.3989422804014327f
#define EXP2C       -0.7213475204444817f   // -0.5*log2(e)
// Abramowitz-Stegun 7.1.25 (3-term), arg pre-scaled by 1/sqrt2 (folded into
// P), 0.5 folded into the coefficients. Phi abs err ~1.3e-5.
#define PHI_P   0.33267253f
#define PHI_C1  0.1740121f
#define PHI_C2 -0.0479399f
#define PHI_C3  0.3739278f

__device__ __forceinline__ float phi_from_exp_s(float u, float e) {
    float t  = __builtin_amdgcn_rcpf(__builtin_fmaf(PHI_P, fabsf(u), 1.0f));
    float hp = __builtin_fmaf(__builtin_fmaf(PHI_C3, t, PHI_C2), t, PHI_C1) * t * e;
    return 0.5f + __builtin_copysignf(0.5f - hp, u);
}

// One block per (b,i) row: Eh row, dvals -> diagonal of covar, xin copy.
__global__ __launch_bounds__(128) void relu_cov_row(
    const float* __restrict__ xin, const float* __restrict__ meanin,
    const float* __restrict__ kin, float* __restrict__ out)
{
    const int row = blockIdx.x;          // b*NN + i
    const int b   = row >> 8;
    const int i   = row & (NN - 1);
    const int tid = threadIdx.x;

    const float kd   = kin[((size_t)b * NN + i) * NN + i] + 1e-6f;
    const float var  = fmaxf(kd, 1e-8f);
    const float stdv = __builtin_amdgcn_sqrtf(var);
    const float rstd = __builtin_amdgcn_rcpf(stdv);

    float dterm = 0.0f;
    if (tid < CC) {
        float m  = meanin[(size_t)row * CC + tid];
        float z  = m * rstd;
        float e  = __builtin_amdgcn_exp2f(z * z * EXP2C);
        float ph = INV_SQRT_2PI * e;
        float Ph = phi_from_exp_s(z, e);
        float Eh = m * Ph + stdv * ph;
        out[EH_OFF + (size_t)row * CC + tid] = Eh;
        dterm = (m * m + var) * Ph + m * stdv * ph - Eh * Eh;
    } else if (tid < CC + 2) {
        int dd = tid - CC;                   // xin copy (d=2)
        out[XIN_OFF + (size_t)row * 2 + dd] = xin[(size_t)row * 2 + dd];
    }

    float v = dterm;
    v += __shfl_down(v, 32, 64);
    v += __shfl_down(v, 16, 64);
    v += __shfl_down(v,  8, 64);
    v += __shfl_down(v,  4, 64);
    v += __shfl_down(v,  2, 64);
    v += __shfl_down(v,  1, 64);
    __shared__ float wsum[2];
    if ((tid & 63) == 0) wsum[tid >> 6] = v;
    __syncthreads();
    if (tid == 0) {
        float dval = fmaxf((wsum[0] + wsum[1]) * (1.0f / 96.0f), 1e-6f);
        out[COV_OFF + ((size_t)b * NN + i) * NN + i] = dval + 1e-6f;
    }
}

// Pair kernel, R1-shaped. Block = (b, i2): the 255 upper-triangle pairs of
// balanced row-pair {i2, 255-i2}; thread p owns pair p for ALL 96 c's, then
// stores covar[i,j] and covar[j,i] itself. No c-split, no reduce, no VGPR cap.
__global__ __launch_bounds__(256) void relu_cov_pair(
    const float* __restrict__ meanin, const float* __restrict__ kin,
    const float* __restrict__ Eh, float* __restrict__ out)
{
    const int blk = blockIdx.x;     // b*128 + i2
    const int b   = blk >> 7;
    const int i2  = blk & 127;
    const int p   = threadIdx.x;

    const int rowA = i2;
    const int rowB = 255 - i2;

    __shared__ __align__(16) float smA[CC], sEA[CC], smB[CC], sEB[CC];
    {
        const float* mA = meanin + ((size_t)(b * NN + rowA)) * CC;
        const float* eA = Eh     + ((size_t)(b * NN + rowA)) * CC;
        const float* mB = meanin + ((size_t)(b * NN + rowB)) * CC;
        const float* eB = Eh     + ((size_t)(b * NN + rowB)) * CC;
        if      (p < 96)  smA[p]       = mA[p];
        else if (p < 192) sEA[p - 96]  = eA[p - 96];
        // second half staged by the same threads (96 more loads)
        if      (p < 96)  smB[p]       = mB[p];
        else if (p < 192) sEB[p - 96]  = eB[p - 96];
    }
    __syncthreads();

    if (p >= 255) return;

    const int  nfirst   = 255 - i2;
    const bool firstSeg = p < nfirst;
    const int  i = firstSeg ? rowA : rowB;
    const int  j = firstSeg ? (i2 + 1 + p) : (p + 1);

    const float* kb  = kin + (size_t)b * NN * NN;
    const float  m00 = kb[i * (NN + 1)] + 1e-6f;
    const float  m11 = kb[j * (NN + 1)] + 1e-6f;
    const float  m01 = kb[i * NN + j];          // == m10 exactly (kin symmetric)

    const float det = __builtin_fmaf(-m01, m01, m00 * m11);
    const float s   = __builtin_amdgcn_sqrtf(fmaxf(det, 1e-8f));
    const float t   = fmaxf(__builtin_amdgcn_sqrtf(m00 + m11 + 2.0f * s), 1e-8f);
    const float rt  = __builtin_amdgcn_rcpf(t);
    const float s00 = (m00 + s) * rt;
    const float s01 = m01 * rt;
    const float s11 = (m11 + s) * rt;
    const float dS  = fmaxf(__builtin_fmaf(-s01, s01, s00 * s11), 1e-8f);
    const float rdS = __builtin_amdgcn_rcpf(dS);
    const float i00 = s11 * rdS;
    const float i01 = -s01 * rdS;
    const float i11 = s00 * rdS;
    // psi brackets collapse: (mj*s00+mi*s01-s00*s01*u1)*phi1 = (qj*mj+qd*mi)*e1
    // with INV_SQRT_2PI folded in; similarly for psi2. 2*s01^2*p1*p2 = c2*e1*e2.
    const float qd = -INV_SQRT_2PI * s01 * s01 * s01 * rdS;
    const float qj =  INV_SQRT_2PI * s00 * s00 * s11 * rdS;
    const float qi =  INV_SQRT_2PI * s00 * s11 * s11 * rdS;
    const float c2 = 2.0f * INV_SQRT_2PI * INV_SQRT_2PI * s01 * s01;

    const float4* mjp = (const float4*)(meanin + ((size_t)(b * NN + j)) * CC);
    const float4* Ejp = (const float4*)(Eh     + ((size_t)(b * NN + j)) * CC);
    const float4* mip = (const float4*)(firstSeg ? smA : smB);
    const float4* Eip = (const float4*)(firstSeg ? sEA : sEB);

    float acc0 = 0.0f, acc1 = 0.0f, acc2 = 0.0f, acc3 = 0.0f;

    auto elem = [&](float mi, float mjv, float Ei, float Ej, float& acc) {
        float u1 = __builtin_fmaf(i01, mjv, i00 * mi);
        float u2 = __builtin_fmaf(i11, mjv, i01 * mi);
        float e1 = __builtin_amdgcn_exp2f(u1 * u1 * EXP2C);
        float e2 = __builtin_amdgcn_exp2f(u2 * u2 * EXP2C);
        float d1 = __builtin_fmaf(PHI_P, fabsf(u1), 1.0f);
        float d2 = __builtin_fmaf(PHI_P, fabsf(u2), 1.0f);
        float rp = __builtin_amdgcn_rcpf(d1 * d2);   // one rcp for both Phi's
        float t1 = d2 * rp;
        float t2 = d1 * rp;
        float hp1 = __builtin_fmaf(__builtin_fmaf(PHI_C3, t1, PHI_C2), t1, PHI_C1) * t1 * e1;
        float hp2 = __builtin_fmaf(__builtin_fmaf(PHI_C3, t2, PHI_C2), t2, PHI_C1) * t2 * e2;
        float Phi1 = 0.5f + __builtin_copysignf(0.5f - hp1, u1);
        float Phi2 = 0.5f + __builtin_copysignf(0.5f - hp2, u2);
        float a  = __builtin_fmaf(mi, mjv, m01);
        float bb = __builtin_fmaf(qd, mi, qj * mjv);
        float cc = __builtin_fmaf(qi, mi, qd * mjv);
        acc = __builtin_fmaf(a,  Phi1 * Phi2, acc);
        acc = __builtin_fmaf(bb, e1 * Phi2,  acc);
        acc = __builtin_fmaf(cc, e2 * Phi1,  acc);
        acc = __builtin_fmaf(c2, e1 * e2,    acc);
        acc = __builtin_fmaf(-Ei, Ej,        acc);
    };

#pragma unroll 4
    for (int q = 0; q < 24; ++q) {
        float4 mj4 = mjp[q];
        float4 Ej4 = Ejp[q];
        float4 mi4 = mip[q];
        float4 Ei4 = Eip[q];
        elem(mi4.x, mj4.x, Ei4.x, Ej4.x, acc0);
        elem(mi4.y, mj4.y, Ei4.y, Ej4.y, acc1);
        elem(mi4.z, mj4.z, Ei4.z, Ej4.z, acc2);
        elem(mi4.w, mj4.w, Ei4.w, Ej4.w, acc3);
    }

    float v = ((acc0 + acc1) + (acc2 + acc3)) * (1.0f / 96.0f);
    out[COV_OFF + ((size_t)(b * NN + i)) * NN + j] = v;
    out[COV_OFF + ((size_t)(b * NN + j)) * NN + i] = v;
}

extern "C" void kernel_launch(void* const* d_in, const int* in_sizes, int n_in,
                              void* d_out, int out_size, void* d_ws, size_t ws_size,
                              hipStream_t stream) {
    const float* xin    = (const float*)d_in[0];
    const float* meanin = (const float*)d_in[1];
    const float* kin    = (const float*)d_in[2];
    float* out = (float*)d_out;

    relu_cov_row<<<BSZ * NN, 128, 0, stream>>>(xin, meanin, kin, out);
    relu_cov_pair<<<BSZ * 128, 256, 0, stream>>>(meanin, kin, out + EH_OFF, out);
}

// Round 6
// 77.720 us; speedup vs baseline: 1.1214x; 1.1214x over previous
//
#include <hip/hip_runtime.h>
#include <math.h>

#define BSZ 4
#define NN  256
#define CC  96
#define TT  16                 // tile side
#define NTILES 136             // 16*17/2 triangular tiles per batch
#define LSTR 52                // LDS row stride (floats): 16B-aligned, 2-way banks

#define XIN_OFF  0
#define EH_OFF   2048          // BSZ*NN*2
#define COV_OFF  100352        // 2048 + BSZ*NN*CC

#define INV_SQRT_2PI 0.3989422804014327f
#define EXP2C       -0.7213475204444817f   // -0.5*log2(e)
// Abramowitz-Stegun 7.1.25 (3-term), arg pre-scaled by 1/sqrt2 (folded into
// P), 0.5 folded into the coefficients. Phi abs err ~1.3e-5.
#define PHI_P   0.33267253f
#define PHI_C1  0.1740121f
#define PHI_C2 -0.0479399f
#define PHI_C3  0.3739278f

__device__ __forceinline__ float phi_from_exp_s(float u, float e) {
    float t  = __builtin_amdgcn_rcpf(__builtin_fmaf(PHI_P, fabsf(u), 1.0f));
    float hp = __builtin_fmaf(__builtin_fmaf(PHI_C3, t, PHI_C2), t, PHI_C1) * t * e;
    return 0.5f + __builtin_copysignf(0.5f - hp, u);
}

__device__ __forceinline__ int tri_offset(int k) {   // tiles before row k
    return k * TT - (k * (k - 1)) / 2;
}
__device__ __forceinline__ void tri_decode(int t, int& ti, int& tj) {
    float disc = 1089.0f - 8.0f * (float)t;          // (2T+1)^2 - 8t, T=16
    ti = (int)((33.0f - __builtin_amdgcn_sqrtf(disc)) * 0.5f);
    while (tri_offset(ti + 1) <= t) ++ti;            // float-precision fixup
    while (tri_offset(ti) > t) --ti;
    tj = ti + (t - tri_offset(ti));
}

// One block per (b,i) row: Eh row, dvals -> diagonal of covar, xin copy.
__global__ __launch_bounds__(128) void relu_cov_row(
    const float* __restrict__ xin, const float* __restrict__ meanin,
    const float* __restrict__ kin, float* __restrict__ out)
{
    const int row = blockIdx.x;          // b*NN + i
    const int b   = row >> 8;
    const int i   = row & (NN - 1);
    const int tid = threadIdx.x;

    const float kd   = kin[((size_t)b * NN + i) * NN + i] + 1e-6f;
    const float var  = fmaxf(kd, 1e-8f);
    const float stdv = __builtin_amdgcn_sqrtf(var);
    const float rstd = __builtin_amdgcn_rcpf(stdv);

    float dterm = 0.0f;
    if (tid < CC) {
        float m  = meanin[(size_t)row * CC + tid];
        float z  = m * rstd;
        float e  = __builtin_amdgcn_exp2f(z * z * EXP2C);
        float ph = INV_SQRT_2PI * e;
        float Ph = phi_from_exp_s(z, e);
        float Eh = m * Ph + stdv * ph;
        out[EH_OFF + (size_t)row * CC + tid] = Eh;
        dterm = (m * m + var) * Ph + m * stdv * ph - Eh * Eh;
    } else if (tid < CC + 2) {
        int dd = tid - CC;                   // xin copy (d=2)
        out[XIN_OFF + (size_t)row * 2 + dd] = xin[(size_t)row * 2 + dd];
    }

    float v = dterm;
    v += __shfl_down(v, 32, 64);
    v += __shfl_down(v, 16, 64);
    v += __shfl_down(v,  8, 64);
    v += __shfl_down(v,  4, 64);
    v += __shfl_down(v,  2, 64);
    v += __shfl_down(v,  1, 64);
    __shared__ float wsum[2];
    if ((tid & 63) == 0) wsum[tid >> 6] = v;
    __syncthreads();
    if (tid == 0) {
        float dval = fmaxf((wsum[0] + wsum[1]) * (1.0f / 96.0f), 1e-6f);
        out[COV_OFF + ((size_t)b * NN + i) * NN + i] = dval + 1e-6f;
    }
}

// Tiled pair kernel. Block = (b, triangular tile (ti,tj), c-half ch).
// Stages 16 i-rows and 16 j-rows of meanin/Eh (48-c chunk) into LDS with
// fully coalesced float4 loads; inner loop reads LDS only. Thread p =
// (i_loc = p>>4, j_loc = p&15). Partial sums to d_ws; combine kernel later.
// Diagonal tiles (ti==tj) compute their i>j half redundantly (harmless).
__global__ __launch_bounds__(256) void relu_cov_pair(
    const float* __restrict__ meanin, const float* __restrict__ kin,
    const float* __restrict__ Eh, float* __restrict__ partial)
{
    const int bx = blockIdx.x;      // b*NTILES + t
    const int b  = bx / NTILES;
    const int t  = bx - b * NTILES;
    const int ch = blockIdx.y;      // c-half 0/1
    const int p  = threadIdx.x;

    int ti, tj;
    tri_decode(t, ti, tj);

    // lds layout: [smi | sEi | smj | sEj], each 16 rows x LSTR floats
    __shared__ __align__(16) float lds[4 * TT * LSTR];
    float* const smi = lds;
    float* const sEi = lds + TT * LSTR;
    float* const smj = lds + 2 * TT * LSTR;
    float* const sEj = lds + 3 * TT * LSTR;

    // stage: 4 arrays x 16 rows x 12 float4 = 768 float4, 3 per thread
    {
        int k = p;
#pragma unroll
        for (int it = 0; it < 3; ++it, k += 256) {
            int arr = k / 192;
            int rem = k - arr * 192;
            int r   = rem / 12;
            int q   = rem - r * 12;
            const float* src = (arr == 0 || arr == 2) ? meanin : Eh;
            int row = ((arr < 2) ? ti : tj) * TT + r;
            float4 v = *((const float4*)(src + ((size_t)(b * NN + row)) * CC + ch * 48) + q);
            float* dst = lds + arr * (TT * LSTR) + r * LSTR + q * 4;
            *(float4*)dst = v;
        }
    }
    __syncthreads();

    const int i_loc = p >> 4;
    const int j_loc = p & 15;
    const int i = ti * TT + i_loc;
    const int j = tj * TT + j_loc;

    const float* kb  = kin + (size_t)b * NN * NN;
    const float  m00 = kb[i * (NN + 1)] + 1e-6f;
    const float  m11 = kb[j * (NN + 1)] + 1e-6f;
    const float  m01 = kb[i * NN + j];          // == m10 exactly (kin symmetric)

    const float det = __builtin_fmaf(-m01, m01, m00 * m11);
    const float s   = __builtin_amdgcn_sqrtf(fmaxf(det, 1e-8f));
    const float tt  = fmaxf(__builtin_amdgcn_sqrtf(m00 + m11 + 2.0f * s), 1e-8f);
    const float rt  = __builtin_amdgcn_rcpf(tt);
    const float s00 = (m00 + s) * rt;
    const float s01 = m01 * rt;
    const float s11 = (m11 + s) * rt;
    const float dS  = fmaxf(__builtin_fmaf(-s01, s01, s00 * s11), 1e-8f);
    const float rdS = __builtin_amdgcn_rcpf(dS);
    const float i00 = s11 * rdS;
    const float i01 = -s01 * rdS;
    const float i11 = s00 * rdS;
    // psi brackets collapse; INV_SQRT_2PI folded in (see R4/R5 derivation).
    const float qd = -INV_SQRT_2PI * s01 * s01 * s01 * rdS;
    const float qj =  INV_SQRT_2PI * s00 * s00 * s11 * rdS;
    const float qi =  INV_SQRT_2PI * s00 * s11 * s11 * rdS;
    const float c2 = 2.0f * INV_SQRT_2PI * INV_SQRT_2PI * s01 * s01;

    const float* Lmi = smi + i_loc * LSTR;
    const float* LEi = sEi + i_loc * LSTR;
    const float* Lmj = smj + j_loc * LSTR;
    const float* LEj = sEj + j_loc * LSTR;

    float acc0 = 0.0f, acc1 = 0.0f, acc2 = 0.0f, acc3 = 0.0f;

    auto elem = [&](float mi, float mjv, float Ei, float Ej, float& acc) {
        float u1 = __builtin_fmaf(i01, mjv, i00 * mi);
        float u2 = __builtin_fmaf(i11, mjv, i01 * mi);
        float e1 = __builtin_amdgcn_exp2f(u1 * u1 * EXP2C);
        float e2 = __builtin_amdgcn_exp2f(u2 * u2 * EXP2C);
        float d1 = __builtin_fmaf(PHI_P, fabsf(u1), 1.0f);
        float d2 = __builtin_fmaf(PHI_P, fabsf(u2), 1.0f);
        float rp = __builtin_amdgcn_rcpf(d1 * d2);   // one rcp for both Phi's
        float t1 = d2 * rp;
        float t2 = d1 * rp;
        float hp1 = __builtin_fmaf(__builtin_fmaf(PHI_C3, t1, PHI_C2), t1, PHI_C1) * t1 * e1;
        float hp2 = __builtin_fmaf(__builtin_fmaf(PHI_C3, t2, PHI_C2), t2, PHI_C1) * t2 * e2;
        float Phi1 = 0.5f + __builtin_copysignf(0.5f - hp1, u1);
        float Phi2 = 0.5f + __builtin_copysignf(0.5f - hp2, u2);
        float a  = __builtin_fmaf(mi, mjv, m01);
        float bb = __builtin_fmaf(qd, mi, qj * mjv);
        float cc = __builtin_fmaf(qi, mi, qd * mjv);
        // Phi2*(a*Phi1 + bb*e1) + e2*(cc*Phi1 + c2*e1) - Ei*Ej
        float ta = __builtin_fmaf(a,  Phi1, bb * e1);
        float tb = __builtin_fmaf(cc, Phi1, c2 * e1);
        acc = __builtin_fmaf(Phi2, ta, acc);
        acc = __builtin_fmaf(e2,   tb, acc);
        acc = __builtin_fmaf(-Ei,  Ej, acc);
    };

#pragma unroll 4
    for (int q = 0; q < 12; ++q) {
        float4 mi4 = *(const float4*)(Lmi + q * 4);
        float4 mj4 = *(const float4*)(Lmj + q * 4);
        float4 Ei4 = *(const float4*)(LEi + q * 4);
        float4 Ej4 = *(const float4*)(LEj + q * 4);
        elem(mi4.x, mj4.x, Ei4.x, Ej4.x, acc0);
        elem(mi4.y, mj4.y, Ei4.y, Ej4.y, acc1);
        elem(mi4.z, mj4.z, Ei4.z, Ej4.z, acc2);
        elem(mi4.w, mj4.w, Ei4.w, Ej4.w, acc3);
    }

    partial[((size_t)bx * 2 + ch) * 256 + p] = (acc0 + acc1) + (acc2 + acc3);
}

// Combine the two c-half partials, scale, mirrored store (strict i<j only;
// diagonal already written by relu_cov_row).
__global__ __launch_bounds__(256) void relu_cov_combine(
    const float* __restrict__ partial, float* __restrict__ out)
{
    const int bx = blockIdx.x;      // b*NTILES + t
    const int b  = bx / NTILES;
    const int t  = bx - b * NTILES;
    const int p  = threadIdx.x;

    int ti, tj;
    tri_decode(t, ti, tj);
    const int i = ti * TT + (p >> 4);
    const int j = tj * TT + (p & 15);
    if (i >= j) return;

    const float* base = partial + ((size_t)bx * 2) * 256 + p;
    float v = (base[0] + base[256]) * (1.0f / 96.0f);

    out[COV_OFF + ((size_t)(b * NN + i)) * NN + j] = v;
    out[COV_OFF + ((size_t)(b * NN + j)) * NN + i] = v;
}

extern "C" void kernel_launch(void* const* d_in, const int* in_sizes, int n_in,
                              void* d_out, int out_size, void* d_ws, size_t ws_size,
                              hipStream_t stream) {
    const float* xin    = (const float*)d_in[0];
    const float* meanin = (const float*)d_in[1];
    const float* kin    = (const float*)d_in[2];
    float* out     = (float*)d_out;
    float* partial = (float*)d_ws;              // 4*136*2*256 floats ~ 1.1 MB

    relu_cov_row<<<BSZ * NN, 128, 0, stream>>>(xin, meanin, kin, out);
    relu_cov_pair<<<dim3(BSZ * NTILES, 2), 256, 0, stream>>>(
        meanin, kin, out + EH_OFF, partial);
    relu_cov_combine<<<BSZ * NTILES, 256, 0, stream>>>(partial, out);
}

// Round 7
// 77.204 us; speedup vs baseline: 1.1289x; 1.0067x over previous
//
#include <hip/hip_runtime.h>
#include <math.h>

#define BSZ 4
#define NN  256
#define CC  96
#define TT  16                 // tile side
#define NTILES 136             // 16*17/2 triangular tiles per batch
#define NCH 4                  // c-chunks
#define CCH 24                 // c's per chunk
#define LSTR 28                // LDS row stride (floats): 16B-aligned, 2-way banks free

#define XIN_OFF  0
#define EH_OFF   2048          // BSZ*NN*2
#define COV_OFF  100352        // 2048 + BSZ*NN*CC

#define INV_SQRT_2PI 0.3989422804014327f
#define EXP2C       -0.7213475204444817f   // -0.5*log2(e)
// Abramowitz-Stegun 7.1.25 (3-term), arg pre-scaled by 1/sqrt2 (folded into
// P), 0.5 folded into the coefficients. Phi abs err ~1.3e-5.
#define PHI_P   0.33267253f
#define PHI_C1  0.1740121f
#define PHI_C2 -0.0479399f
#define PHI_C3  0.3739278f

__device__ __forceinline__ float phi_from_exp_s(float u, float e) {
    float t  = __builtin_amdgcn_rcpf(__builtin_fmaf(PHI_P, fabsf(u), 1.0f));
    float hp = __builtin_fmaf(__builtin_fmaf(PHI_C3, t, PHI_C2), t, PHI_C1) * t * e;
    return 0.5f + __builtin_copysignf(0.5f - hp, u);
}

__device__ __forceinline__ int tri_offset(int k) {   // tiles before row k
    return k * TT - (k * (k - 1)) / 2;
}
__device__ __forceinline__ void tri_decode(int t, int& ti, int& tj) {
    float disc = 1089.0f - 8.0f * (float)t;          // (2T+1)^2 - 8t, T=16
    ti = (int)((33.0f - __builtin_amdgcn_sqrtf(disc)) * 0.5f);
    while (tri_offset(ti + 1) <= t) ++ti;            // float-precision fixup
    while (tri_offset(ti) > t) --ti;
    tj = ti + (t - tri_offset(ti));
}

// One block per (b,i) row: Eh row, dvals -> diagonal of covar, xin copy.
__global__ __launch_bounds__(128) void relu_cov_row(
    const float* __restrict__ xin, const float* __restrict__ meanin,
    const float* __restrict__ kin, float* __restrict__ out)
{
    const int row = blockIdx.x;          // b*NN + i
    const int b   = row >> 8;
    const int i   = row & (NN - 1);
    const int tid = threadIdx.x;

    const float kd   = kin[((size_t)b * NN + i) * NN + i] + 1e-6f;
    const float var  = fmaxf(kd, 1e-8f);
    const float stdv = __builtin_amdgcn_sqrtf(var);
    const float rstd = __builtin_amdgcn_rcpf(stdv);

    float dterm = 0.0f;
    if (tid < CC) {
        float m  = meanin[(size_t)row * CC + tid];
        float z  = m * rstd;
        float e  = __builtin_amdgcn_exp2f(z * z * EXP2C);
        float ph = INV_SQRT_2PI * e;
        float Ph = phi_from_exp_s(z, e);
        float Eh = m * Ph + stdv * ph;
        out[EH_OFF + (size_t)row * CC + tid] = Eh;
        dterm = (m * m + var) * Ph + m * stdv * ph - Eh * Eh;
    } else if (tid < CC + 2) {
        int dd = tid - CC;                   // xin copy (d=2)
        out[XIN_OFF + (size_t)row * 2 + dd] = xin[(size_t)row * 2 + dd];
    }

    float v = dterm;
    v += __shfl_down(v, 32, 64);
    v += __shfl_down(v, 16, 64);
    v += __shfl_down(v,  8, 64);
    v += __shfl_down(v,  4, 64);
    v += __shfl_down(v,  2, 64);
    v += __shfl_down(v,  1, 64);
    __shared__ float wsum[2];
    if ((tid & 63) == 0) wsum[tid >> 6] = v;
    __syncthreads();
    if (tid == 0) {
        float dval = fmaxf((wsum[0] + wsum[1]) * (1.0f / 96.0f), 1e-6f);
        out[COV_OFF + ((size_t)b * NN + i) * NN + i] = dval + 1e-6f;
    }
}

// Tiled pair kernel. Block = (b, triangular tile (ti,tj), c-chunk ch of 4).
// Stages 16 i-rows and 16 j-rows of meanin/Eh (24-c chunk) into LDS with
// coalesced float4 loads; inner loop reads LDS only. Thread p =
// (i_loc = p>>4, j_loc = p&15). Partial sums to d_ws; combine kernel later.
// Grid 2176 blocks (8.5/CU); launch_bounds(256,6) -> VGPR<=85, 6 waves/SIMD.
__global__ __launch_bounds__(256, 6) void relu_cov_pair(
    const float* __restrict__ meanin, const float* __restrict__ kin,
    const float* __restrict__ Eh, float* __restrict__ partial)
{
    const int bx = blockIdx.x;      // b*NTILES + t
    const int b  = bx / NTILES;
    const int t  = bx - b * NTILES;
    const int ch = blockIdx.y;      // c-chunk 0..3
    const int p  = threadIdx.x;

    int ti, tj;
    tri_decode(t, ti, tj);

    // lds layout: [smi | sEi | smj | sEj], each 16 rows x LSTR floats
    __shared__ __align__(16) float lds[4 * TT * LSTR];
    float* const smi = lds;
    float* const sEi = lds + TT * LSTR;
    float* const smj = lds + 2 * TT * LSTR;
    float* const sEj = lds + 3 * TT * LSTR;

    // stage: 4 arrays x 16 rows x 6 float4 = 384 float4, 1.5 per thread
    {
#pragma unroll
        for (int it = 0; it < 2; ++it) {
            int k = p + it * 256;
            if (k < 384) {
                int arr = k / 96;
                int rem = k - arr * 96;
                int r   = rem / 6;
                int q   = rem - r * 6;
                const float* src = (arr == 0 || arr == 2) ? meanin : Eh;
                int row = ((arr < 2) ? ti : tj) * TT + r;
                float4 v = *((const float4*)(src + ((size_t)(b * NN + row)) * CC + ch * CCH) + q);
                float* dst = lds + arr * (TT * LSTR) + r * LSTR + q * 4;
                *(float4*)dst = v;
            }
        }
    }
    __syncthreads();

    const int i_loc = p >> 4;
    const int j_loc = p & 15;
    const int i = ti * TT + i_loc;
    const int j = tj * TT + j_loc;

    const float* kb  = kin + (size_t)b * NN * NN;
    const float  m00 = kb[i * (NN + 1)] + 1e-6f;
    const float  m11 = kb[j * (NN + 1)] + 1e-6f;
    const float  m01 = kb[i * NN + j];          // == m10 exactly (kin symmetric)

    const float det = __builtin_fmaf(-m01, m01, m00 * m11);
    const float s   = __builtin_amdgcn_sqrtf(fmaxf(det, 1e-8f));
    const float tt  = fmaxf(__builtin_amdgcn_sqrtf(m00 + m11 + 2.0f * s), 1e-8f);
    const float rt  = __builtin_amdgcn_rcpf(tt);
    const float s00 = (m00 + s) * rt;
    const float s01 = m01 * rt;
    const float s11 = (m11 + s) * rt;
    const float dS  = fmaxf(__builtin_fmaf(-s01, s01, s00 * s11), 1e-8f);
    const float rdS = __builtin_amdgcn_rcpf(dS);
    const float i00 = s11 * rdS;
    const float i01 = -s01 * rdS;
    const float i11 = s00 * rdS;
    // psi brackets collapse; INV_SQRT_2PI folded in (see R4/R5 derivation).
    const float qd = -INV_SQRT_2PI * s01 * s01 * s01 * rdS;
    const float qj =  INV_SQRT_2PI * s00 * s00 * s11 * rdS;
    const float qi =  INV_SQRT_2PI * s00 * s11 * s11 * rdS;
    const float c2 = 2.0f * INV_SQRT_2PI * INV_SQRT_2PI * s01 * s01;

    const float* Lmi = smi + i_loc * LSTR;
    const float* LEi = sEi + i_loc * LSTR;
    const float* Lmj = smj + j_loc * LSTR;
    const float* LEj = sEj + j_loc * LSTR;

    float acc0 = 0.0f, acc1 = 0.0f, acc2 = 0.0f, acc3 = 0.0f;

    auto elem = [&](float mi, float mjv, float Ei, float Ej, float& acc) {
        float u1 = __builtin_fmaf(i01, mjv, i00 * mi);
        float u2 = __builtin_fmaf(i11, mjv, i01 * mi);
        float e1 = __builtin_amdgcn_exp2f(u1 * u1 * EXP2C);
        float e2 = __builtin_amdgcn_exp2f(u2 * u2 * EXP2C);
        float d1 = __builtin_fmaf(PHI_P, fabsf(u1), 1.0f);
        float d2 = __builtin_fmaf(PHI_P, fabsf(u2), 1.0f);
        float rp = __builtin_amdgcn_rcpf(d1 * d2);   // one rcp for both Phi's
        float t1 = d2 * rp;
        float t2 = d1 * rp;
        float hp1 = __builtin_fmaf(__builtin_fmaf(PHI_C3, t1, PHI_C2), t1, PHI_C1) * t1 * e1;
        float hp2 = __builtin_fmaf(__builtin_fmaf(PHI_C3, t2, PHI_C2), t2, PHI_C1) * t2 * e2;
        float Phi1 = 0.5f + __builtin_copysignf(0.5f - hp1, u1);
        float Phi2 = 0.5f + __builtin_copysignf(0.5f - hp2, u2);
        float a  = __builtin_fmaf(mi, mjv, m01);
        float bb = __builtin_fmaf(qd, mi, qj * mjv);
        float cc = __builtin_fmaf(qi, mi, qd * mjv);
        // Phi2*(a*Phi1 + bb*e1) + e2*(cc*Phi1 + c2*e1) - Ei*Ej
        float ta = __builtin_fmaf(a,  Phi1, bb * e1);
        float tb = __builtin_fmaf(cc, Phi1, c2 * e1);
        acc = __builtin_fmaf(Phi2, ta, acc);
        acc = __builtin_fmaf(e2,   tb, acc);
        acc = __builtin_fmaf(-Ei,  Ej, acc);
    };

#pragma unroll
    for (int q = 0; q < 6; ++q) {
        float4 mi4 = *(const float4*)(Lmi + q * 4);
        float4 mj4 = *(const float4*)(Lmj + q * 4);
        float4 Ei4 = *(const float4*)(LEi + q * 4);
        float4 Ej4 = *(const float4*)(LEj + q * 4);
        elem(mi4.x, mj4.x, Ei4.x, Ej4.x, acc0);
        elem(mi4.y, mj4.y, Ei4.y, Ej4.y, acc1);
        elem(mi4.z, mj4.z, Ei4.z, Ej4.z, acc2);
        elem(mi4.w, mj4.w, Ei4.w, Ej4.w, acc3);
    }

    partial[((size_t)bx * NCH + ch) * 256 + p] = (acc0 + acc1) + (acc2 + acc3);
}

// Combine the four c-chunk partials, scale, mirrored store (strict i<j only;
// diagonal already written by relu_cov_row).
__global__ __launch_bounds__(256) void relu_cov_combine(
    const float* __restrict__ partial, float* __restrict__ out)
{
    const int bx = blockIdx.x;      // b*NTILES + t
    const int b  = bx / NTILES;
    const int t  = bx - b * NTILES;
    const int p  = threadIdx.x;

    int ti, tj;
    tri_decode(t, ti, tj);
    const int i = ti * TT + (p >> 4);
    const int j = tj * TT + (p & 15);
    if (i >= j) return;

    const float* base = partial + ((size_t)bx * NCH) * 256 + p;
    float v = ((base[0] + base[256]) + (base[512] + base[768])) * (1.0f / 96.0f);

    out[COV_OFF + ((size_t)(b * NN + i)) * NN + j] = v;
    out[COV_OFF + ((size_t)(b * NN + j)) * NN + i] = v;
}

extern "C" void kernel_launch(void* const* d_in, const int* in_sizes, int n_in,
                              void* d_out, int out_size, void* d_ws, size_t ws_size,
                              hipStream_t stream) {
    const float* xin    = (const float*)d_in[0];
    const float* meanin = (const float*)d_in[1];
    const float* kin    = (const float*)d_in[2];
    float* out     = (float*)d_out;
    float* partial = (float*)d_ws;              // 4*136*4*256 floats ~ 2.2 MB

    relu_cov_row<<<BSZ * NN, 128, 0, stream>>>(xin, meanin, kin, out);
    relu_cov_pair<<<dim3(BSZ * NTILES, NCH), 256, 0, stream>>>(
        meanin, kin, out + EH_OFF, partial);
    relu_cov_combine<<<BSZ * NTILES, 256, 0, stream>>>(partial, out);
}

// Round 8
// 77.190 us; speedup vs baseline: 1.1291x; 1.0002x over previous
//
#include <hip/hip_runtime.h>
#include <math.h>

#define BSZ 4
#define NN  256
#define CC  96
#define TT  16                 // tile side
#define NTILES 136             // 16*17/2 triangular tiles per batch
#define RSTR 100               // LDS row stride (floats): 16B-aligned, 2-way banks free
#define ARR  (TT * RSTR)       // 1600 floats per array

#define XIN_OFF  0
#define EH_OFF   2048          // BSZ*NN*2
#define COV_OFF  100352        // 2048 + BSZ*NN*CC

#define INV_SQRT_2PI 0.3989422804014327f
#define EXP2C       -0.7213475204444817f   // -0.5*log2(e)
// Abramowitz-Stegun 7.1.25 (3-term), arg pre-scaled by 1/sqrt2 (folded into
// P), 0.5 folded into the coefficients. Phi abs err ~1.3e-5.
#define PHI_P   0.33267253f
#define PHI_C1  0.1740121f
#define PHI_C2 -0.0479399f
#define PHI_C3  0.3739278f

__device__ __forceinline__ float phi_from_exp_s(float u, float e) {
    float t  = __builtin_amdgcn_rcpf(__builtin_fmaf(PHI_P, fabsf(u), 1.0f));
    float hp = __builtin_fmaf(__builtin_fmaf(PHI_C3, t, PHI_C2), t, PHI_C1) * t * e;
    return 0.5f + __builtin_copysignf(0.5f - hp, u);
}

__device__ __forceinline__ int tri_offset(int k) {   // tiles before row k
    return k * TT - (k * (k - 1)) / 2;
}
__device__ __forceinline__ void tri_decode(int t, int& ti, int& tj) {
    float disc = 1089.0f - 8.0f * (float)t;          // (2T+1)^2 - 8t, T=16
    ti = (int)((33.0f - __builtin_amdgcn_sqrtf(disc)) * 0.5f);
    while (tri_offset(ti + 1) <= t) ++ti;            // float-precision fixup
    while (tri_offset(ti) > t) --ti;
    tj = ti + (t - tri_offset(ti));
}

// Single fused kernel. Block = (b, triangular tile (ti,tj)), 512 threads.
// Phase 1: stage meanin rows (16 i-rows + 16 j-rows, full 96 c) to LDS,
//          compute per-row std consts from kin diag.
// Phase 2: compute Eh for all 32 rows in LDS (bitwise-deterministic, so
//          every block agrees; no inter-kernel dependency).
// Phase 2b (diagonal tiles only): write Eh output, xin copy, dvals diagonal.
// Phase 3: pair loop — thread = (c-half h = tid>>8, pair p = tid&255),
//          48 c's each; LDS reduce across halves; mirrored store (i<j).
__global__ __launch_bounds__(512) void relu_cov_fused(
    const float* __restrict__ xin, const float* __restrict__ meanin,
    const float* __restrict__ kin, float* __restrict__ out)
{
    const int blk = blockIdx.x;     // b*NTILES + t
    const int b   = blk / NTILES;
    const int t   = blk - b * NTILES;
    const int tid = threadIdx.x;

    int ti, tj;
    tri_decode(t, ti, tj);
    const bool diag = (ti == tj);

    __shared__ __align__(16) float lds[4 * ARR];   // [smi | sEi | smj | sEj]
    __shared__ float red[512];
    __shared__ float srowS[32], srowR[32], srowV[32];
    float* const smi = lds;
    float* const sEi = lds + ARR;
    float* const smj = lds + 2 * ARR;
    float* const sEj = lds + 3 * ARR;

    // --- Phase 1: row consts + stage meanin ---
    if (tid < 32) {
        int row = (tid < 16) ? (ti * TT + tid) : (tj * TT + (tid - 16));
        float kd  = kin[((size_t)(b * NN + row)) * NN + row] + 1e-6f;
        float var = fmaxf(kd, 1e-8f);
        float st  = __builtin_amdgcn_sqrtf(var);
        srowV[tid] = var;
        srowS[tid] = st;
        srowR[tid] = __builtin_amdgcn_rcpf(st);
    }
#pragma unroll
    for (int it = 0; it < 2; ++it) {
        int k = tid + it * 512;         // 2 arrays x 16 rows x 24 float4 = 768
        if (k < 768) {
            int arr = k / 384;          // 0 = i-rows, 1 = j-rows
            int rem = k - arr * 384;
            int r   = rem / 24;
            int q   = rem - r * 24;
            int row = ((arr == 0) ? ti : tj) * TT + r;
            float4 v = *((const float4*)(meanin + ((size_t)(b * NN + row)) * CC) + q);
            *(float4*)(lds + arr * 2 * ARR + r * RSTR + q * 4) = v;
        }
    }
    __syncthreads();

    // --- Phase 2: Eh for 32 rows (2 arrays x 16 x 96 = 3072, 6/thread) ---
#pragma unroll
    for (int it = 0; it < 6; ++it) {
        int k   = tid + it * 512;
        int arr = k / 1536;
        int rem = k - arr * 1536;
        int r   = rem / 96;
        int c   = rem - r * 96;
        float m  = lds[arr * 2 * ARR + r * RSTR + c];
        float st = srowS[arr * 16 + r];
        float rs = srowR[arr * 16 + r];
        float z  = m * rs;
        float e  = __builtin_amdgcn_exp2f(z * z * EXP2C);
        float Ph = phi_from_exp_s(z, e);
        float Eh = __builtin_fmaf(m, Ph, st * (INV_SQRT_2PI * e));
        lds[(arr * 2 + 1) * ARR + r * RSTR + c] = Eh;
    }
    __syncthreads();

    // --- Phase 2b: diagonal-tile global outputs ---
    if (diag) {
#pragma unroll
        for (int it = 0; it < 3; ++it) {         // Eh output: 16 x 96
            int k = tid + it * 512;
            int r = k / 96, c = k - r * 96;
            out[EH_OFF + ((size_t)(b * NN + ti * TT + r)) * CC + c] = sEi[r * RSTR + c];
        }
        if (tid < 32) {                          // xin copy: 16 rows x 2
            int r = tid >> 1, d = tid & 1;
            size_t o = ((size_t)(b * NN + ti * TT + r)) * 2 + d;
            out[XIN_OFF + o] = xin[o];
        }
        {                                        // dvals: tid = r*32 + s, 3 c each
            int r = tid >> 5, s = tid & 31;
            float st = srowS[r], var = srowV[r], rs = srowR[r];
            float dsum = 0.0f;
#pragma unroll
            for (int dc = 0; dc < 3; ++dc) {
                int c = s * 3 + dc;
                float m  = smi[r * RSTR + c];
                float Eh = sEi[r * RSTR + c];
                float z  = m * rs;
                float e  = __builtin_amdgcn_exp2f(z * z * EXP2C);
                float Ph = phi_from_exp_s(z, e);
                float ph = INV_SQRT_2PI * e;
                float dt = __builtin_fmaf(__builtin_fmaf(m, m, var), Ph,
                           __builtin_fmaf(m * st, ph, -Eh * Eh));
                dsum += dt;
            }
            dsum += __shfl_down(dsum, 16, 32);
            dsum += __shfl_down(dsum,  8, 32);
            dsum += __shfl_down(dsum,  4, 32);
            dsum += __shfl_down(dsum,  2, 32);
            dsum += __shfl_down(dsum,  1, 32);
            if (s == 0) {
                float dval = fmaxf(dsum * (1.0f / 96.0f), 1e-6f);
                int row = ti * TT + r;
                out[COV_OFF + ((size_t)(b * NN + row)) * NN + row] = dval + 1e-6f;
            }
        }
    }

    // --- Phase 3: pair loop ---
    const int p     = tid & 255;
    const int h     = tid >> 8;        // c-half 0/1
    const int i_loc = p >> 4;
    const int j_loc = p & 15;
    const int i = ti * TT + i_loc;
    const int j = tj * TT + j_loc;

    const float m00 = srowV[i_loc];         // == kdiag_i + 1e-6 (clip non-binding)
    const float m11 = srowV[16 + j_loc];
    const float m01 = kin[((size_t)(b * NN + i)) * NN + j];   // == m10 (symmetric)

    const float det = __builtin_fmaf(-m01, m01, m00 * m11);
    const float s   = __builtin_amdgcn_sqrtf(fmaxf(det, 1e-8f));
    const float tt  = fmaxf(__builtin_amdgcn_sqrtf(m00 + m11 + 2.0f * s), 1e-8f);
    const float rt  = __builtin_amdgcn_rcpf(tt);
    const float s00 = (m00 + s) * rt;
    const float s01 = m01 * rt;
    const float s11 = (m11 + s) * rt;
    const float dS  = fmaxf(__builtin_fmaf(-s01, s01, s00 * s11), 1e-8f);
    const float rdS = __builtin_amdgcn_rcpf(dS);
    const float i00 = s11 * rdS;
    const float i01 = -s01 * rdS;
    const float i11 = s00 * rdS;
    // psi brackets collapse; INV_SQRT_2PI folded in (see R4/R5 derivation).
    const float qd = -INV_SQRT_2PI * s01 * s01 * s01 * rdS;
    const float qj =  INV_SQRT_2PI * s00 * s00 * s11 * rdS;
    const float qi =  INV_SQRT_2PI * s00 * s11 * s11 * rdS;
    const float c2 = 2.0f * INV_SQRT_2PI * INV_SQRT_2PI * s01 * s01;

    const float* Lmi = smi + i_loc * RSTR + h * 48;
    const float* LEi = sEi + i_loc * RSTR + h * 48;
    const float* Lmj = smj + j_loc * RSTR + h * 48;
    const float* LEj = sEj + j_loc * RSTR + h * 48;

    float acc0 = 0.0f, acc1 = 0.0f, acc2 = 0.0f, acc3 = 0.0f;

    auto elem = [&](float mi, float mjv, float Ei, float Ej, float& acc) {
        float u1 = __builtin_fmaf(i01, mjv, i00 * mi);
        float u2 = __builtin_fmaf(i11, mjv, i01 * mi);
        float e1 = __builtin_amdgcn_exp2f(u1 * u1 * EXP2C);
        float e2 = __builtin_amdgcn_exp2f(u2 * u2 * EXP2C);
        float d1 = __builtin_fmaf(PHI_P, fabsf(u1), 1.0f);
        float d2 = __builtin_fmaf(PHI_P, fabsf(u2), 1.0f);
        float rp = __builtin_amdgcn_rcpf(d1 * d2);   // one rcp for both Phi's
        float t1 = d2 * rp;
        float t2 = d1 * rp;
        float hp1 = __builtin_fmaf(__builtin_fmaf(PHI_C3, t1, PHI_C2), t1, PHI_C1) * t1 * e1;
        float hp2 = __builtin_fmaf(__builtin_fmaf(PHI_C3, t2, PHI_C2), t2, PHI_C1) * t2 * e2;
        float Phi1 = 0.5f + __builtin_copysignf(0.5f - hp1, u1);
        float Phi2 = 0.5f + __builtin_copysignf(0.5f - hp2, u2);
        float a  = __builtin_fmaf(mi, mjv, m01);
        float bb = __builtin_fmaf(qd, mi, qj * mjv);
        float cc = __builtin_fmaf(qi, mi, qd * mjv);
        // Phi2*(a*Phi1 + bb*e1) + e2*(cc*Phi1 + c2*e1) - Ei*Ej
        float ta = __builtin_fmaf(a,  Phi1, bb * e1);
        float tb = __builtin_fmaf(cc, Phi1, c2 * e1);
        acc = __builtin_fmaf(Phi2, ta, acc);
        acc = __builtin_fmaf(e2,   tb, acc);
        acc = __builtin_fmaf(-Ei,  Ej, acc);
    };

#pragma unroll 4
    for (int q = 0; q < 12; ++q) {
        float4 mi4 = *(const float4*)(Lmi + q * 4);
        float4 mj4 = *(const float4*)(Lmj + q * 4);
        float4 Ei4 = *(const float4*)(LEi + q * 4);
        float4 Ej4 = *(const float4*)(LEj + q * 4);
        elem(mi4.x, mj4.x, Ei4.x, Ej4.x, acc0);
        elem(mi4.y, mj4.y, Ei4.y, Ej4.y, acc1);
        elem(mi4.z, mj4.z, Ei4.z, Ej4.z, acc2);
        elem(mi4.w, mj4.w, Ei4.w, Ej4.w, acc3);
    }

    red[tid] = (acc0 + acc1) + (acc2 + acc3);
    __syncthreads();

    if (tid < 256 && i < j) {
        float v = (red[tid] + red[tid + 256]) * (1.0f / 96.0f);
        out[COV_OFF + ((size_t)(b * NN + i)) * NN + j] = v;
        out[COV_OFF + ((size_t)(b * NN + j)) * NN + i] = v;
    }
}

extern "C" void kernel_launch(void* const* d_in, const int* in_sizes, int n_in,
                              void* d_out, int out_size, void* d_ws, size_t ws_size,
                              hipStream_t stream) {
    const float* xin    = (const float*)d_in[0];
    const float* meanin = (const float*)d_in[1];
    const float* kin    = (const float*)d_in[2];
    float* out = (float*)d_out;

    relu_cov_fused<<<BSZ * NTILES, 512, 0, stream>>>(xin, meanin, kin, out);
}